// Round 2
// baseline (310.361 us; speedup 1.0000x reference)
//
#include <hip/hip_runtime.h>
#include <hip/hip_bf16.h>

#define N_SEND 12288
#define N_REC  49152
#define NEDGE  196608

typedef __attribute__((ext_vector_type(8)))  short short8;
typedef __attribute__((ext_vector_type(4)))  short shortx4;
typedef __attribute__((ext_vector_type(4)))  float floatx4;
typedef __attribute__((ext_vector_type(16))) float floatx16;
typedef __attribute__((ext_vector_type(4)))  unsigned int uintx4;

__device__ inline short f2bs(float f) {
    __hip_bfloat16 h = __float2bfloat16(f);
    return *reinterpret_cast<short*>(&h);
}
// jax.nn.gelu default approximate=True (tanh form)
__device__ inline float gelu_tanh(float x) {
    const float k0 = 0.7978845608028654f;
    float u = k0 * (x + 0.044715f * x * x * x);
    float e = __expf(2.0f * u);
    float t = 1.0f - 2.0f / (e + 1.0f);
    return 0.5f * x * (1.0f + t);
}

// ---- prep: BT1[n][0:256]=Wl1lo^T, BT1[n][256:512]=(We2@Wl1hi)^T, WT2=Wl2^T, cvec=be2@Wl1hi
__global__ void prep_kernel(const float* __restrict__ We2, const float* __restrict__ be2,
                            const float* __restrict__ Wl1, const float* __restrict__ Wl2,
                            short* __restrict__ BT1, short* __restrict__ WT2,
                            float* __restrict__ cvec) {
    int i = blockIdx.x;
    int n = threadIdx.x;
    if (i < 256) {
        float acc = 0.f;
        for (int j = 0; j < 256; ++j)
            acc += We2[i * 256 + j] * Wl1[(256 + j) * 256 + n];
        BT1[n * 512 + i]       = f2bs(Wl1[i * 256 + n]);   // k<256: Wl1lo
        BT1[n * 512 + 256 + i] = f2bs(acc);                // k>=256: M = We2@Wl1hi
        WT2[n * 256 + i]       = f2bs(Wl2[i * 256 + n]);
    } else {
        float acc = 0.f;
        for (int j = 0; j < 256; ++j)
            acc += be2[j] * Wl1[(256 + j) * 256 + n];
        cvec[n] = acc;
    }
}

// ---- xcast: Xb = bf16(X), [2][N_SEND][256]
__global__ void xcast_kernel(const float* __restrict__ X, short* __restrict__ Xb) {
    int i = (blockIdx.x * 256 + threadIdx.x) * 8;
    floatx4 v0 = *(const floatx4*)(X + i);
    floatx4 v1 = *(const floatx4*)(X + i + 4);
    short8 p;
#pragma unroll
    for (int j = 0; j < 4; ++j) { p[j] = f2bs(v0[j]); p[j + 4] = f2bs(v1[j]); }
    *(short8*)(Xb + i) = p;
}

// ---- bounds: bnd[r] = lower_bound(idx_rec, r), r in [0, N_REC]
__global__ void bounds_kernel(const int* __restrict__ idx_rec, int* __restrict__ bnd) {
    int r = blockIdx.x * 256 + threadIdx.x;
    if (r > N_REC) return;
    int lo = 0, hi = NEDGE;
    while (lo < hi) { int mid = (lo + hi) >> 1; if (idx_rec[mid] < r) lo = mid + 1; else hi = mid; }
    bnd[r] = lo;
}

// LDS tile indexing (short index). XOR swizzle: spreads phase-1 fragment writes
// (stride 1024B / 512B -> single-bank without swizzle) across 8 banks, while
// GEMM reads (row varies with lane) stay a bijective permutation of a
// contiguous 512B block -> conflict-free. Same macro on write & read sides.
#define XTU(f, row) ((((f) * 64) + ((row) ^ ((f) & 7))) * 8)
#define HTU(f, rl)  ((((f) * 32) + ((rl) ^ ((f) & 7))) * 8)

// ==== fused32: 32 receivers/block, 512 threads = 8 waves, ~48.3 KB LDS -> 3 blocks/CU.
// phase 1: per-receiver serial aggregation (1 recv at a time -> lean VGPRs),
//          direct global reads (scalar-uniform idx/EA), fragments into swizzled LDS.
// phase 2: GEMM1 K=512 ([X|H] @ BT1^T) + gelu -> T in LDS; GEMM2 K=256 -> OUT.
// Rows: row = rt*32 + m; rt = batch, m = block-local receiver. H shared across rt.
__global__ __launch_bounds__(512, 6)
void fused32(const int* __restrict__ idx_send, const int* __restrict__ bnd,
             const float* __restrict__ EA, const float* __restrict__ We1,
             const float* __restrict__ be1, const short* __restrict__ Xb,
             const short* __restrict__ BT1, const short* __restrict__ WT2,
             const float* __restrict__ cvec, const float* __restrict__ bl1,
             const float* __restrict__ bl2, float* __restrict__ OUT) {
    __shared__ __attribute__((aligned(16))) short XT[32 * 64 * 8];  // 32 KB; reused for T
    __shared__ __attribute__((aligned(16))) short HT[32 * 32 * 8];  // 16 KB
    __shared__ int sb[33];

    int t = threadIdx.x;
    int r0 = blockIdx.x * 32;
    if (t <= 32) sb[t] = bnd[r0 + t];
    __syncthreads();

    // ---------------- phase 1: aggregate ----------------
    {
        int cg = t & 31;          // 8-col group
        int b  = (t >> 5) & 1;    // batch
        int rh = t >> 6;          // wave id: receivers rh*4 .. rh*4+3
        int c8 = cg * 8;
        int hc = c8 + 4 * b;

        floatx4 w0 = *(const floatx4*)(We1 + hc);
        floatx4 w1 = *(const floatx4*)(We1 + 256 + hc);
        floatx4 w2 = *(const floatx4*)(We1 + 512 + hc);
        floatx4 w3 = *(const floatx4*)(We1 + 768 + hc);
        floatx4 bb = *(const floatx4*)(be1 + hc);
        const short* xb_t = Xb + (size_t)b * N_SEND * 256 + c8;

#pragma unroll
        for (int r = 0; r < 4; ++r) {
            int rl = rh * 4 + r;
            int es = __builtin_amdgcn_readfirstlane(sb[rl]);
            int ee = __builtin_amdgcn_readfirstlane(sb[rl + 1]);

            float xacc[8];
            float hacc[4];
#pragma unroll
            for (int c = 0; c < 8; ++c) xacc[c] = 0.f;
#pragma unroll
            for (int c = 0; c < 4; ++c) hacc[c] = 0.f;

            for (int e = es; e < ee; ++e) {
                int s = idx_send[e];                                   // wave-uniform
                floatx4 a = *(const floatx4*)(EA + (size_t)e * 4);     // wave-uniform
                uintx4 xv = *(const uintx4*)(xb_t + (size_t)s * 256);
#pragma unroll
                for (int dw = 0; dw < 4; ++dw) {
                    xacc[2 * dw]     += __builtin_bit_cast(float, xv[dw] << 16);
                    xacc[2 * dw + 1] += __builtin_bit_cast(float, xv[dw] & 0xffff0000u);
                }
#pragma unroll
                for (int j = 0; j < 4; ++j) {
                    float u = a[0] * w0[j] + a[1] * w1[j] + a[2] * w2[j] + a[3] * w3[j] + bb[j];
                    hacc[j] += gelu_tanh(u);
                }
            }
            short8 xp;
#pragma unroll
            for (int c = 0; c < 8; ++c) xp[c] = f2bs(xacc[c]);
            *(short8*)(XT + XTU(cg, b * 32 + rl)) = xp;
            shortx4 hp;
#pragma unroll
            for (int c = 0; c < 4; ++c) hp[c] = f2bs(hacc[c]);
            *(shortx4*)(HT + HTU(cg, rl) + 4 * b) = hp;
        }
    }
    __syncthreads();

    // ---------------- GEMM1 (K=512) ----------------
    int w = t >> 6, lane = t & 63;
    int m = lane & 31, q = lane >> 5;
    int wcol = w * 32;
    floatx16 acc0, acc1;
#pragma unroll
    for (int j = 0; j < 16; ++j) { acc0[j] = 0.f; acc1[j] = 0.f; }

    const short* Bp1 = BT1 + (size_t)(wcol + m) * 512 + q * 8;
#pragma unroll
    for (int ci = 0; ci < 8; ++ci) {
        short8 bf[4];
#pragma unroll
        for (int kk = 0; kk < 4; ++kk) bf[kk] = *(const short8*)(Bp1 + ci * 64 + kk * 16);
#pragma unroll
        for (int kk = 0; kk < 4; ++kk) {
            int f = ci * 8 + 2 * kk + q;
            short8 a0, a1;
            if (ci < 4) {
                a0 = *(const short8*)(XT + XTU(f, m));
                a1 = *(const short8*)(XT + XTU(f, 32 + m));
            } else {
                a0 = *(const short8*)(HT + HTU(f - 32, m));
                a1 = a0;   // H shared across batches
            }
            acc0 = __builtin_amdgcn_mfma_f32_32x32x16_bf16(bf[kk], a0, acc0, 0, 0, 0);
            acc1 = __builtin_amdgcn_mfma_f32_32x32x16_bf16(bf[kk], a1, acc1, 0, 0, 0);
        }
    }
    __syncthreads();   // all waves done reading XT/HT

    // ---- epilogue1: gelu(acc + cnt*cvec + bl1) -> T (into XT, fragment-major) ----
    {
        float cntv = (float)(sb[m + 1] - sb[m]);
#pragma unroll
        for (int qd = 0; qd < 4; ++qd) {
            int c0 = wcol + qd * 8 + q * 4;
            floatx4 cv  = *(const floatx4*)(cvec + c0);
            floatx4 b1v = *(const floatx4*)(bl1 + c0);
            shortx4 p0, p1;
#pragma unroll
            for (int j = 0; j < 4; ++j) {
                p0[j] = f2bs(gelu_tanh(acc0[qd * 4 + j] + cntv * cv[j] + b1v[j]));
                p1[j] = f2bs(gelu_tanh(acc1[qd * 4 + j] + cntv * cv[j] + b1v[j]));
            }
            *(shortx4*)(XT + XTU(w * 4 + qd, m)      + q * 4) = p0;
            *(shortx4*)(XT + XTU(w * 4 + qd, 32 + m) + q * 4) = p1;
        }
#pragma unroll
        for (int j = 0; j < 16; ++j) { acc0[j] = 0.f; acc1[j] = 0.f; }
    }
    __syncthreads();

    // ---------------- GEMM2 (K=256): T @ WT2^T ----------------
    const short* Bp2 = WT2 + (size_t)(wcol + m) * 256 + q * 8;
#pragma unroll
    for (int ci = 0; ci < 4; ++ci) {
        short8 bf[4];
#pragma unroll
        for (int kk = 0; kk < 4; ++kk) bf[kk] = *(const short8*)(Bp2 + ci * 64 + kk * 16);
#pragma unroll
        for (int kk = 0; kk < 4; ++kk) {
            int f2 = ci * 8 + 2 * kk + q;
            short8 a0 = *(const short8*)(XT + XTU(f2, m));
            short8 a1 = *(const short8*)(XT + XTU(f2, 32 + m));
            acc0 = __builtin_amdgcn_mfma_f32_32x32x16_bf16(bf[kk], a0, acc0, 0, 0, 0);
            acc1 = __builtin_amdgcn_mfma_f32_32x32x16_bf16(bf[kk], a1, acc1, 0, 0, 0);
        }
    }

    // ---- epilogue2: + bl2 -> OUT (rt = batch, receiver = r0 + m) ----
#pragma unroll
    for (int rt = 0; rt < 2; ++rt) {
        const floatx16& ac = rt ? acc1 : acc0;
        size_t obase = ((size_t)rt * N_REC + r0 + m) * 256;
#pragma unroll
        for (int qd = 0; qd < 4; ++qd) {
            int c0 = wcol + qd * 8 + q * 4;
            floatx4 bv = *(const floatx4*)(bl2 + c0);
            floatx4 o;
#pragma unroll
            for (int j = 0; j < 4; ++j)
                o[j] = ac[qd * 4 + j] + bv[j];
            *(floatx4*)(OUT + obase + c0) = o;
        }
    }
}

extern "C" void kernel_launch(void* const* d_in, const int* in_sizes, int n_in,
                              void* d_out, int out_size, void* d_ws, size_t ws_size,
                              hipStream_t stream) {
    const float* x        = (const float*)d_in[0];
    const float* ea       = (const float*)d_in[1];
    const int*   idx_send = (const int*)d_in[2];
    const int*   idx_rec  = (const int*)d_in[3];
    const float* We1      = (const float*)d_in[4];
    const float* be1      = (const float*)d_in[5];
    const float* We2      = (const float*)d_in[6];
    const float* be2      = (const float*)d_in[7];
    const float* Wl1      = (const float*)d_in[8];
    const float* bl1      = (const float*)d_in[9];
    const float* Wl2      = (const float*)d_in[10];
    const float* bl2      = (const float*)d_in[11];
    float* out = (float*)d_out;
    char*  ws  = (char*)d_ws;

    short* BT1  = (short*)(ws + 0);           // 262144 B
    short* WT2  = (short*)(ws + 262144);      // 131072 B
    float* cvec = (float*)(ws + 393216);      // 1024 B
    int*   bnd  = (int*)  (ws + 397312);      // 196612 B
    short* Xb   = (short*)(ws + 1048576);     // 12.58 MB

    prep_kernel<<<257, 256, 0, stream>>>(We2, be2, Wl1, Wl2, BT1, WT2, cvec);
    xcast_kernel<<<(2 * N_SEND * 256) / (256 * 8), 256, 0, stream>>>(x, Xb);
    bounds_kernel<<<(N_REC + 1 + 255) / 256, 256, 0, stream>>>(idx_rec, bnd);
    fused32<<<N_REC / 32, 512, 0, stream>>>(idx_send, bnd, ea, We1, be1, Xb,
                                            BT1, WT2, cvec, bl1, bl2, out);
}

// Round 3
// 280.511 us; speedup vs baseline: 1.1064x; 1.1064x over previous
//
#include <hip/hip_runtime.h>
#include <hip/hip_bf16.h>

#define N_SEND 12288
#define N_REC  49152
#define NEDGE  196608
#define RECV   48          // receivers per block; M = 96 rows = 3 row-tiles

typedef __attribute__((ext_vector_type(8)))  short short8;
typedef __attribute__((ext_vector_type(4)))  short shortx4;
typedef __attribute__((ext_vector_type(4)))  float floatx4;
typedef __attribute__((ext_vector_type(16))) float floatx16;
typedef __attribute__((ext_vector_type(4)))  unsigned int uintx4;

__device__ inline short f2bs(float f) {
    __hip_bfloat16 h = __float2bfloat16(f);
    return *reinterpret_cast<short*>(&h);
}
// jax.nn.gelu default approximate=True (tanh form)
__device__ inline float gelu_tanh(float x) {
    const float k0 = 0.7978845608028654f;
    float u = k0 * (x + 0.044715f * x * x * x);
    float e = __expf(2.0f * u);
    float t = 1.0f - 2.0f / (e + 1.0f);
    return 0.5f * x * (1.0f + t);
}

// ---- prep: BT1[n][0:256]=Wl1lo^T, BT1[n][256:512]=(We2@Wl1hi)^T, WT2=Wl2^T, cvec=be2@Wl1hi
__global__ void prep_kernel(const float* __restrict__ We2, const float* __restrict__ be2,
                            const float* __restrict__ Wl1, const float* __restrict__ Wl2,
                            short* __restrict__ BT1, short* __restrict__ WT2,
                            float* __restrict__ cvec) {
    int i = blockIdx.x;
    int n = threadIdx.x;
    if (i < 256) {
        float acc = 0.f;
        for (int j = 0; j < 256; ++j)
            acc += We2[i * 256 + j] * Wl1[(256 + j) * 256 + n];
        BT1[n * 512 + i]       = f2bs(Wl1[i * 256 + n]);   // k<256: Wl1lo
        BT1[n * 512 + 256 + i] = f2bs(acc);                // k>=256: M = We2@Wl1hi
        WT2[n * 256 + i]       = f2bs(Wl2[i * 256 + n]);
    } else {
        float acc = 0.f;
        for (int j = 0; j < 256; ++j)
            acc += be2[j] * Wl1[(256 + j) * 256 + n];
        cvec[n] = acc;
    }
}

// ---- xcast: Xb = bf16(X), [2][N_SEND][256]
__global__ void xcast_kernel(const float* __restrict__ X, short* __restrict__ Xb) {
    int i = (blockIdx.x * 256 + threadIdx.x) * 8;
    floatx4 v0 = *(const floatx4*)(X + i);
    floatx4 v1 = *(const floatx4*)(X + i + 4);
    short8 p;
#pragma unroll
    for (int j = 0; j < 4; ++j) { p[j] = f2bs(v0[j]); p[j + 4] = f2bs(v1[j]); }
    *(short8*)(Xb + i) = p;
}

// ---- bounds: bnd[r] = lower_bound(idx_rec, r), r in [0, N_REC]
__global__ void bounds_kernel(const int* __restrict__ idx_rec, int* __restrict__ bnd) {
    int r = blockIdx.x * 256 + threadIdx.x;
    if (r > N_REC) return;
    int lo = 0, hi = NEDGE;
    while (lo < hi) { int mid = (lo + hi) >> 1; if (idx_rec[mid] < r) lo = mid + 1; else hi = mid; }
    bnd[r] = lo;
}

// LDS tile indexing. XOR swizzle: spreads phase-1 fragment writes (which would
// otherwise hit one bank) across 8 banks; GEMM reads stay a bijective
// permutation within each 8-row group -> conflict-free. Same macro both sides.
// XT rows: 96 (= batch*48 + rl). HT rows: 48 (rl), batch halves at +4b shorts.
#define XTU(f, row) ((((f) * 96) + ((row) ^ ((f) & 7))) * 8)
#define HTU(f, rl)  ((((f) * 48) + ((rl) ^ ((f) & 7))) * 8)

// ==== fused48: 48 receivers/block, 512 threads = 8 waves, ~72.4 KB LDS -> 2 blocks/CU.
// phase 1: per-receiver serial aggregation, direct scalar idx/EA loads with 1-deep
//          prefetch, fragments into swizzled LDS.
// phase 2: GEMM1 K=512 ([X|H] @ BT1^T) + gelu -> T in LDS; GEMM2 K=256 -> OUT.
// Rows: r = rt*32 + m (rt=0..2); batch = r>=48; rl = r - 48*batch.
__global__ __launch_bounds__(512, 4)
void fused48(const int* __restrict__ idx_send, const int* __restrict__ bnd,
             const float* __restrict__ EA, const float* __restrict__ We1,
             const float* __restrict__ be1, const short* __restrict__ Xb,
             const short* __restrict__ BT1, const short* __restrict__ WT2,
             const float* __restrict__ cvec, const float* __restrict__ bl1,
             const float* __restrict__ bl2, float* __restrict__ OUT) {
    __shared__ __attribute__((aligned(16))) short XT[32 * 96 * 8];  // 48 KB; reused for T
    __shared__ __attribute__((aligned(16))) short HT[32 * 48 * 8];  // 24 KB
    __shared__ int sb[RECV + 1];

    int t = threadIdx.x;
    int r0 = blockIdx.x * RECV;
    if (t <= RECV) sb[t] = bnd[r0 + t];
    __syncthreads();

    // ---------------- phase 1: aggregate ----------------
    {
        int cg = t & 31;          // 8-col group
        int b  = (t >> 5) & 1;    // batch
        int rh = t >> 6;          // wave id: receivers rh*6 .. rh*6+5
        int c8 = cg * 8;
        int hc = c8 + 4 * b;

        floatx4 w0 = *(const floatx4*)(We1 + hc);
        floatx4 w1 = *(const floatx4*)(We1 + 256 + hc);
        floatx4 w2 = *(const floatx4*)(We1 + 512 + hc);
        floatx4 w3 = *(const floatx4*)(We1 + 768 + hc);
        floatx4 bb = *(const floatx4*)(be1 + hc);
        const short* xb_t = Xb + (size_t)b * N_SEND * 256 + c8;

#pragma unroll
        for (int r = 0; r < 6; ++r) {
            int rl = rh * 6 + r;
            int es = __builtin_amdgcn_readfirstlane(sb[rl]);
            int ee = __builtin_amdgcn_readfirstlane(sb[rl + 1]);

            float xacc[8];
            float hacc[4];
#pragma unroll
            for (int c = 0; c < 8; ++c) xacc[c] = 0.f;
#pragma unroll
            for (int c = 0; c < 4; ++c) hacc[c] = 0.f;

            int s = 0; floatx4 a = {0.f, 0.f, 0.f, 0.f};
            if (es < ee) { s = idx_send[es]; a = *(const floatx4*)(EA + (size_t)es * 4); }
            for (int e = es; e < ee; ++e) {
                int cs = s; floatx4 ca = a;
                int ep = (e + 1 < ee) ? e + 1 : e;          // branchless 1-deep prefetch
                s = idx_send[ep];
                a = *(const floatx4*)(EA + (size_t)ep * 4);
                uintx4 xv = *(const uintx4*)(xb_t + (size_t)cs * 256);
#pragma unroll
                for (int dw = 0; dw < 4; ++dw) {
                    xacc[2 * dw]     += __builtin_bit_cast(float, xv[dw] << 16);
                    xacc[2 * dw + 1] += __builtin_bit_cast(float, xv[dw] & 0xffff0000u);
                }
#pragma unroll
                for (int j = 0; j < 4; ++j) {
                    float u = ca[0] * w0[j] + ca[1] * w1[j] + ca[2] * w2[j] + ca[3] * w3[j] + bb[j];
                    hacc[j] += gelu_tanh(u);
                }
            }
            short8 xp;
#pragma unroll
            for (int c = 0; c < 8; ++c) xp[c] = f2bs(xacc[c]);
            *(short8*)(XT + XTU(cg, b * RECV + rl)) = xp;
            shortx4 hp;
#pragma unroll
            for (int c = 0; c < 4; ++c) hp[c] = f2bs(hacc[c]);
            *(shortx4*)(HT + HTU(cg, rl) + 4 * b) = hp;
        }
    }
    __syncthreads();

    // ---------------- GEMM1 (K=512) ----------------
    int w = t >> 6, lane = t & 63;
    int m = lane & 31, q = lane >> 5;
    int wcol = w * 32;
    floatx16 acc[3];
#pragma unroll
    for (int i = 0; i < 3; ++i)
#pragma unroll
        for (int j = 0; j < 16; ++j) acc[i][j] = 0.f;

    const short* Bp1 = BT1 + (size_t)(wcol + m) * 512 + q * 8;
#pragma unroll
    for (int ci = 0; ci < 8; ++ci) {
#pragma unroll
        for (int kk = 0; kk < 4; ++kk) {
            short8 bv = *(const short8*)(Bp1 + ci * 64 + kk * 16);
            int f = ci * 8 + 2 * kk + q;
            short8 a0, a1, a2;
            if (ci < 4) {
                a0 = *(const short8*)(XT + XTU(f, m));
                a1 = *(const short8*)(XT + XTU(f, 32 + m));
                a2 = *(const short8*)(XT + XTU(f, 64 + m));
            } else {
                int fh = f - 32;
                a0 = *(const short8*)(HT + HTU(fh, m));                   // rows 0..31  -> rl=m
                int rl1 = (m < 16) ? 32 + m : m - 16;                     // rows 32..63
                a1 = *(const short8*)(HT + HTU(fh, rl1));
                a2 = *(const short8*)(HT + HTU(fh, 16 + m));              // rows 64..95 -> rl=16+m
            }
            acc[0] = __builtin_amdgcn_mfma_f32_32x32x16_bf16(bv, a0, acc[0], 0, 0, 0);
            acc[1] = __builtin_amdgcn_mfma_f32_32x32x16_bf16(bv, a1, acc[1], 0, 0, 0);
            acc[2] = __builtin_amdgcn_mfma_f32_32x32x16_bf16(bv, a2, acc[2], 0, 0, 0);
        }
    }
    __syncthreads();   // all waves done reading XT/HT

    // ---- epilogue1: gelu(acc + cnt*cvec + bl1) -> T (into XT, fragment-major) ----
#pragma unroll
    for (int qd = 0; qd < 4; ++qd) {
        int c0 = wcol + qd * 8 + q * 4;
        floatx4 cv  = *(const floatx4*)(cvec + c0);
        floatx4 b1v = *(const floatx4*)(bl1 + c0);
#pragma unroll
        for (int rt = 0; rt < 3; ++rt) {
            int r = rt * 32 + m;
            int bat = (r >= RECV) ? 1 : 0;
            int rl = r - RECV * bat;
            float cntv = (float)(sb[rl + 1] - sb[rl]);
            shortx4 pk;
#pragma unroll
            for (int j = 0; j < 4; ++j)
                pk[j] = f2bs(gelu_tanh(acc[rt][qd * 4 + j] + cntv * cv[j] + b1v[j]));
            *(shortx4*)(XT + XTU(w * 4 + qd, r) + q * 4) = pk;
        }
    }
#pragma unroll
    for (int i = 0; i < 3; ++i)
#pragma unroll
        for (int j = 0; j < 16; ++j) acc[i][j] = 0.f;
    __syncthreads();

    // ---------------- GEMM2 (K=256): T @ WT2^T ----------------
    const short* Bp2 = WT2 + (size_t)(wcol + m) * 256 + q * 8;
#pragma unroll
    for (int ci = 0; ci < 4; ++ci) {
#pragma unroll
        for (int kk = 0; kk < 4; ++kk) {
            short8 bv = *(const short8*)(Bp2 + ci * 64 + kk * 16);
            int f2 = ci * 8 + 2 * kk + q;
            short8 a0 = *(const short8*)(XT + XTU(f2, m));
            short8 a1 = *(const short8*)(XT + XTU(f2, 32 + m));
            short8 a2 = *(const short8*)(XT + XTU(f2, 64 + m));
            acc[0] = __builtin_amdgcn_mfma_f32_32x32x16_bf16(bv, a0, acc[0], 0, 0, 0);
            acc[1] = __builtin_amdgcn_mfma_f32_32x32x16_bf16(bv, a1, acc[1], 0, 0, 0);
            acc[2] = __builtin_amdgcn_mfma_f32_32x32x16_bf16(bv, a2, acc[2], 0, 0, 0);
        }
    }

    // ---- epilogue2: + bl2 -> OUT ----
#pragma unroll
    for (int rt = 0; rt < 3; ++rt) {
        int r = rt * 32 + m;
        int bat = (r >= RECV) ? 1 : 0;
        int rl = r - RECV * bat;
        size_t obase = ((size_t)bat * N_REC + r0 + rl) * 256;
#pragma unroll
        for (int qd = 0; qd < 4; ++qd) {
            int c0 = wcol + qd * 8 + q * 4;
            floatx4 bv = *(const floatx4*)(bl2 + c0);
            floatx4 o;
#pragma unroll
            for (int j = 0; j < 4; ++j)
                o[j] = acc[rt][qd * 4 + j] + bv[j];
            *(floatx4*)(OUT + obase + c0) = o;
        }
    }
}

extern "C" void kernel_launch(void* const* d_in, const int* in_sizes, int n_in,
                              void* d_out, int out_size, void* d_ws, size_t ws_size,
                              hipStream_t stream) {
    const float* x        = (const float*)d_in[0];
    const float* ea       = (const float*)d_in[1];
    const int*   idx_send = (const int*)d_in[2];
    const int*   idx_rec  = (const int*)d_in[3];
    const float* We1      = (const float*)d_in[4];
    const float* be1      = (const float*)d_in[5];
    const float* We2      = (const float*)d_in[6];
    const float* be2      = (const float*)d_in[7];
    const float* Wl1      = (const float*)d_in[8];
    const float* bl1      = (const float*)d_in[9];
    const float* Wl2      = (const float*)d_in[10];
    const float* bl2      = (const float*)d_in[11];
    float* out = (float*)d_out;
    char*  ws  = (char*)d_ws;

    short* BT1  = (short*)(ws + 0);           // 262144 B
    short* WT2  = (short*)(ws + 262144);      // 131072 B
    float* cvec = (float*)(ws + 393216);      // 1024 B
    int*   bnd  = (int*)  (ws + 397312);      // 196612 B
    short* Xb   = (short*)(ws + 1048576);     // 12.58 MB

    prep_kernel<<<257, 256, 0, stream>>>(We2, be2, Wl1, Wl2, BT1, WT2, cvec);
    xcast_kernel<<<(2 * N_SEND * 256) / (256 * 8), 256, 0, stream>>>(x, Xb);
    bounds_kernel<<<(N_REC + 1 + 255) / 256, 256, 0, stream>>>(idx_rec, bnd);
    fused48<<<N_REC / RECV, 512, 0, stream>>>(idx_send, bnd, ea, We1, be1, Xb,
                                              BT1, WT2, cvec, bl1, bl2, out);
}

// Round 4
// 274.590 us; speedup vs baseline: 1.1303x; 1.0216x over previous
//
#include <hip/hip_runtime.h>
#include <hip/hip_bf16.h>

#define N_SEND 12288
#define N_REC  49152
#define NEDGE  196608
#define RECV   48          // receivers per block; M = 96 rows = 3 row-tiles

typedef __attribute__((ext_vector_type(8)))  short short8;
typedef __attribute__((ext_vector_type(4)))  short shortx4;
typedef __attribute__((ext_vector_type(4)))  float floatx4;
typedef __attribute__((ext_vector_type(16))) float floatx16;
typedef __attribute__((ext_vector_type(4)))  unsigned int uintx4;

__device__ inline short f2bs(float f) {
    __hip_bfloat16 h = __float2bfloat16(f);
    return *reinterpret_cast<short*>(&h);
}
// jax.nn.gelu default approximate=True (tanh form)
__device__ inline float gelu_tanh(float x) {
    const float k0 = 0.7978845608028654f;
    float u = k0 * (x + 0.044715f * x * x * x);
    float e = __expf(2.0f * u);
    float t = 1.0f - 2.0f / (e + 1.0f);
    return 0.5f * x * (1.0f + t);
}

// ---- prep: BT1[n][0:256]=Wl1lo^T, BT1[n][256:512]=(We2@Wl1hi)^T, WT2=Wl2^T, cvec=be2@Wl1hi
__global__ void prep_kernel(const float* __restrict__ We2, const float* __restrict__ be2,
                            const float* __restrict__ Wl1, const float* __restrict__ Wl2,
                            short* __restrict__ BT1, short* __restrict__ WT2,
                            float* __restrict__ cvec) {
    int i = blockIdx.x;
    int n = threadIdx.x;
    if (i < 256) {
        float acc = 0.f;
        for (int j = 0; j < 256; ++j)
            acc += We2[i * 256 + j] * Wl1[(256 + j) * 256 + n];
        BT1[n * 512 + i]       = f2bs(Wl1[i * 256 + n]);   // k<256: Wl1lo
        BT1[n * 512 + 256 + i] = f2bs(acc);                // k>=256: M = We2@Wl1hi
        WT2[n * 256 + i]       = f2bs(Wl2[i * 256 + n]);
    } else {
        float acc = 0.f;
        for (int j = 0; j < 256; ++j)
            acc += be2[j] * Wl1[(256 + j) * 256 + n];
        cvec[n] = acc;
    }
}

// ---- xcast: Xb = bf16(X), interleaved [send][batch][256] (edge's 1KB contiguous)
__global__ void xcast_kernel(const float* __restrict__ X, short* __restrict__ Xb) {
    int i = (blockIdx.x * 256 + threadIdx.x) * 8;
    int row = i >> 8;                 // b*N_SEND + n
    int c   = i & 255;
    int bb_ = (row >= N_SEND) ? 1 : 0;
    int n   = row - bb_ * N_SEND;
    floatx4 v0 = *(const floatx4*)(X + i);
    floatx4 v1 = *(const floatx4*)(X + i + 4);
    short8 p;
#pragma unroll
    for (int j = 0; j < 4; ++j) { p[j] = f2bs(v0[j]); p[j + 4] = f2bs(v1[j]); }
    *(short8*)(Xb + (size_t)n * 512 + bb_ * 256 + c) = p;
}

// ---- bounds: bnd[r] = lower_bound(idx_rec, r), r in [0, N_REC]
__global__ void bounds_kernel(const int* __restrict__ idx_rec, int* __restrict__ bnd) {
    int r = blockIdx.x * 256 + threadIdx.x;
    if (r > N_REC) return;
    int lo = 0, hi = NEDGE;
    while (lo < hi) { int mid = (lo + hi) >> 1; if (idx_rec[mid] < r) lo = mid + 1; else hi = mid; }
    bnd[r] = lo;
}

// LDS tile indexing. XOR swizzle both sides (write & read use the same bijection).
#define XTU(f, row) ((((f) * 96) + ((row) ^ ((f) & 7))) * 8)
#define HTU(f, rl)  ((((f) * 48) + ((rl) ^ ((f) & 7))) * 8)

// ==== fused48: 48 receivers/block, 512 threads = 8 waves, ~72.4 KB LDS -> 2 blocks/CU.
// phase 1: flattened per-wave edge stream, ping-pong 4-edge chunks (4-8 gathers in
//          flight), scalar-uniform receiver-boundary flush into swizzled LDS.
// phase 2: GEMM1 K=512 ([X|H] @ BT1^T) + gelu -> T in LDS; GEMM2 K=256 -> OUT.
__global__ __launch_bounds__(512, 4)
void fused48(const int* __restrict__ idx_send, const int* __restrict__ bnd,
             const float* __restrict__ EA, const float* __restrict__ We1,
             const float* __restrict__ be1, const short* __restrict__ Xb,
             const short* __restrict__ BT1, const short* __restrict__ WT2,
             const float* __restrict__ cvec, const float* __restrict__ bl1,
             const float* __restrict__ bl2, float* __restrict__ OUT) {
    __shared__ __attribute__((aligned(16))) short XT[32 * 96 * 8];  // 48 KB; reused for T
    __shared__ __attribute__((aligned(16))) short HT[32 * 48 * 8];  // 24 KB
    __shared__ int sb[RECV + 9];   // +8 pad: FLUSH_R may read one past the last bound

    int t = threadIdx.x;
    int r0 = blockIdx.x * RECV;
    if (t <= RECV) sb[t] = bnd[r0 + t];
    __syncthreads();

    // ---------------- phase 1: aggregate (pipelined edge stream) ----------------
    {
        int cg = t & 31;          // 8-col group
        int b  = (t >> 5) & 1;    // batch
        int rh = t >> 6;          // wave id: receivers rh*6 .. rh*6+5
        int c8 = cg * 8;
        int hc = c8 + 4 * b;

        floatx4 w0 = *(const floatx4*)(We1 + hc);
        floatx4 w1 = *(const floatx4*)(We1 + 256 + hc);
        floatx4 w2 = *(const floatx4*)(We1 + 512 + hc);
        floatx4 w3 = *(const floatx4*)(We1 + 768 + hc);
        floatx4 bb = *(const floatx4*)(be1 + hc);
        const short* xb_t = Xb + b * 256 + c8;   // interleaved: row s at s*512

        int rl0 = rh * 6;
        int e0 = __builtin_amdgcn_readfirstlane(sb[rl0]);
        int eN = __builtin_amdgcn_readfirstlane(sb[rl0 + 6]);

        float xacc[8];
        float hacc[4];
#pragma unroll
        for (int c = 0; c < 8; ++c) xacc[c] = 0.f;
#pragma unroll
        for (int c = 0; c < 4; ++c) hacc[c] = 0.f;

        int rcur = rl0;
        int bend = __builtin_amdgcn_readfirstlane(sb[rcur + 1]);

#define FLUSH_R() {                                                          \
        short8 xp_; shortx4 hp_;                                             \
        _Pragma("unroll")                                                    \
        for (int c_ = 0; c_ < 8; ++c_) xp_[c_] = f2bs(xacc[c_]);             \
        *(short8*)(XT + XTU(cg, b * RECV + rcur)) = xp_;                     \
        _Pragma("unroll")                                                    \
        for (int c_ = 0; c_ < 4; ++c_) hp_[c_] = f2bs(hacc[c_]);             \
        *(shortx4*)(HT + HTU(cg, rcur) + 4 * b) = hp_;                       \
        _Pragma("unroll")                                                    \
        for (int c_ = 0; c_ < 8; ++c_) xacc[c_] = 0.f;                       \
        _Pragma("unroll")                                                    \
        for (int c_ = 0; c_ < 4; ++c_) hacc[c_] = 0.f;                       \
        ++rcur;                                                              \
        bend = __builtin_amdgcn_readfirstlane(sb[rcur + 1]);                 \
    }

#define LOADC(S, A, XV, base) {                                              \
        _Pragma("unroll")                                                    \
        for (int j_ = 0; j_ < 4; ++j_) {                                     \
            int ei_ = (base) + j_; ei_ = (ei_ < eN) ? ei_ : (eN - 1);        \
            S[j_] = idx_send[ei_];                                           \
            A[j_] = *(const floatx4*)(EA + (size_t)ei_ * 4);                 \
        }                                                                    \
        _Pragma("unroll")                                                    \
        for (int j_ = 0; j_ < 4; ++j_)                                       \
            XV[j_] = *(const uintx4*)(xb_t + (size_t)S[j_] * 512);           \
    }

#define CONSUME1(av, xvv, ej) {                                              \
        if ((ej) < eN) {                                                     \
            while ((ej) == bend) FLUSH_R();                                  \
            uintx4 xv_ = (xvv);                                              \
            _Pragma("unroll")                                                \
            for (int dw_ = 0; dw_ < 4; ++dw_) {                              \
                xacc[2 * dw_]     += __builtin_bit_cast(float, xv_[dw_] << 16);          \
                xacc[2 * dw_ + 1] += __builtin_bit_cast(float, xv_[dw_] & 0xffff0000u);  \
            }                                                                \
            floatx4 a_ = (av);                                               \
            _Pragma("unroll")                                                \
            for (int jj_ = 0; jj_ < 4; ++jj_) {                              \
                float u_ = a_[0] * w0[jj_] + a_[1] * w1[jj_] + a_[2] * w2[jj_] \
                         + a_[3] * w3[jj_] + bb[jj_];                        \
                hacc[jj_] += gelu_tanh(u_);                                  \
            }                                                                \
        }                                                                    \
    }

        if (e0 < eN) {
            int sA[4], sB[4];
            floatx4 aA[4], aB[4];
            uintx4 xvA[4], xvB[4];
            int e = e0;
            LOADC(sA, aA, xvA, e);
            for (;;) {
                int moreB = (e + 4 < eN);
                if (moreB) LOADC(sB, aB, xvB, e + 4);
#pragma unroll
                for (int j = 0; j < 4; ++j) CONSUME1(aA[j], xvA[j], e + j);
                e += 4;
                if (!moreB) break;
                int moreA = (e + 4 < eN);
                if (moreA) LOADC(sA, aA, xvA, e + 4);
#pragma unroll
                for (int j = 0; j < 4; ++j) CONSUME1(aB[j], xvB[j], e + j);
                e += 4;
                if (!moreA) break;
            }
        }
        // tail: flush current + any remaining (possibly empty) receivers
        while (rcur < rl0 + 6) FLUSH_R();
    }
    __syncthreads();

    // ---------------- GEMM1 (K=512) ----------------
    int w = t >> 6, lane = t & 63;
    int m = lane & 31, q = lane >> 5;
    int wcol = w * 32;
    floatx16 acc[3];
#pragma unroll
    for (int i = 0; i < 3; ++i)
#pragma unroll
        for (int j = 0; j < 16; ++j) acc[i][j] = 0.f;

    const short* Bp1 = BT1 + (size_t)(wcol + m) * 512 + q * 8;
#pragma unroll
    for (int ci = 0; ci < 8; ++ci) {
#pragma unroll
        for (int kk = 0; kk < 4; ++kk) {
            short8 bv = *(const short8*)(Bp1 + ci * 64 + kk * 16);
            int f = ci * 8 + 2 * kk + q;
            short8 a0, a1, a2;
            if (ci < 4) {
                a0 = *(const short8*)(XT + XTU(f, m));
                a1 = *(const short8*)(XT + XTU(f, 32 + m));
                a2 = *(const short8*)(XT + XTU(f, 64 + m));
            } else {
                int fh = f - 32;
                a0 = *(const short8*)(HT + HTU(fh, m));                   // rows 0..31  -> rl=m
                int rl1 = (m < 16) ? 32 + m : m - 16;                     // rows 32..63
                a1 = *(const short8*)(HT + HTU(fh, rl1));
                a2 = *(const short8*)(HT + HTU(fh, 16 + m));              // rows 64..95 -> rl=16+m
            }
            acc[0] = __builtin_amdgcn_mfma_f32_32x32x16_bf16(bv, a0, acc[0], 0, 0, 0);
            acc[1] = __builtin_amdgcn_mfma_f32_32x32x16_bf16(bv, a1, acc[1], 0, 0, 0);
            acc[2] = __builtin_amdgcn_mfma_f32_32x32x16_bf16(bv, a2, acc[2], 0, 0, 0);
        }
    }
    __syncthreads();   // all waves done reading XT/HT

    // ---- epilogue1: gelu(acc + cnt*cvec + bl1) -> T (into XT, fragment-major) ----
#pragma unroll
    for (int qd = 0; qd < 4; ++qd) {
        int c0 = wcol + qd * 8 + q * 4;
        floatx4 cv  = *(const floatx4*)(cvec + c0);
        floatx4 b1v = *(const floatx4*)(bl1 + c0);
#pragma unroll
        for (int rt = 0; rt < 3; ++rt) {
            int r = rt * 32 + m;
            int bat = (r >= RECV) ? 1 : 0;
            int rl = r - RECV * bat;
            float cntv = (float)(sb[rl + 1] - sb[rl]);
            shortx4 pk;
#pragma unroll
            for (int j = 0; j < 4; ++j)
                pk[j] = f2bs(gelu_tanh(acc[rt][qd * 4 + j] + cntv * cv[j] + b1v[j]));
            *(shortx4*)(XT + XTU(w * 4 + qd, r) + q * 4) = pk;
        }
    }
#pragma unroll
    for (int i = 0; i < 3; ++i)
#pragma unroll
        for (int j = 0; j < 16; ++j) acc[i][j] = 0.f;
    __syncthreads();

    // ---------------- GEMM2 (K=256): T @ WT2^T ----------------
    const short* Bp2 = WT2 + (size_t)(wcol + m) * 256 + q * 8;
#pragma unroll
    for (int ci = 0; ci < 4; ++ci) {
#pragma unroll
        for (int kk = 0; kk < 4; ++kk) {
            short8 bv = *(const short8*)(Bp2 + ci * 64 + kk * 16);
            int f2 = ci * 8 + 2 * kk + q;
            short8 a0 = *(const short8*)(XT + XTU(f2, m));
            short8 a1 = *(const short8*)(XT + XTU(f2, 32 + m));
            short8 a2 = *(const short8*)(XT + XTU(f2, 64 + m));
            acc[0] = __builtin_amdgcn_mfma_f32_32x32x16_bf16(bv, a0, acc[0], 0, 0, 0);
            acc[1] = __builtin_amdgcn_mfma_f32_32x32x16_bf16(bv, a1, acc[1], 0, 0, 0);
            acc[2] = __builtin_amdgcn_mfma_f32_32x32x16_bf16(bv, a2, acc[2], 0, 0, 0);
        }
    }

    // ---- epilogue2: + bl2 -> OUT ----
#pragma unroll
    for (int rt = 0; rt < 3; ++rt) {
        int r = rt * 32 + m;
        int bat = (r >= RECV) ? 1 : 0;
        int rl = r - RECV * bat;
        size_t obase = ((size_t)bat * N_REC + r0 + rl) * 256;
#pragma unroll
        for (int qd = 0; qd < 4; ++qd) {
            int c0 = wcol + qd * 8 + q * 4;
            floatx4 bv = *(const floatx4*)(bl2 + c0);
            floatx4 o;
#pragma unroll
            for (int j = 0; j < 4; ++j)
                o[j] = acc[rt][qd * 4 + j] + bv[j];
            *(floatx4*)(OUT + obase + c0) = o;
        }
    }
}

extern "C" void kernel_launch(void* const* d_in, const int* in_sizes, int n_in,
                              void* d_out, int out_size, void* d_ws, size_t ws_size,
                              hipStream_t stream) {
    const float* x        = (const float*)d_in[0];
    const float* ea       = (const float*)d_in[1];
    const int*   idx_send = (const int*)d_in[2];
    const int*   idx_rec  = (const int*)d_in[3];
    const float* We1      = (const float*)d_in[4];
    const float* be1      = (const float*)d_in[5];
    const float* We2      = (const float*)d_in[6];
    const float* be2      = (const float*)d_in[7];
    const float* Wl1      = (const float*)d_in[8];
    const float* bl1      = (const float*)d_in[9];
    const float* Wl2      = (const float*)d_in[10];
    const float* bl2      = (const float*)d_in[11];
    float* out = (float*)d_out;
    char*  ws  = (char*)d_ws;

    short* BT1  = (short*)(ws + 0);           // 262144 B
    short* WT2  = (short*)(ws + 262144);      // 131072 B
    float* cvec = (float*)(ws + 393216);      // 1024 B
    int*   bnd  = (int*)  (ws + 397312);      // 196612 B
    short* Xb   = (short*)(ws + 1048576);     // 12.58 MB

    prep_kernel<<<257, 256, 0, stream>>>(We2, be2, Wl1, Wl2, BT1, WT2, cvec);
    xcast_kernel<<<(2 * N_SEND * 256) / (256 * 8), 256, 0, stream>>>(x, Xb);
    bounds_kernel<<<(N_REC + 1 + 255) / 256, 256, 0, stream>>>(idx_rec, bnd);
    fused48<<<N_REC / RECV, 512, 0, stream>>>(idx_send, bnd, ea, We1, be1, Xb,
                                              BT1, WT2, cvec, bl1, bl2, out);
}